// Round 12
// baseline (78.214 us; speedup 1.0000x reference)
//
#include <hip/hip_runtime.h>

typedef __attribute__((ext_vector_type(4))) float f32x4;
typedef __attribute__((ext_vector_type(8))) __bf16 bf16x8;
typedef __attribute__((ext_vector_type(8))) unsigned short ushort8;

__device__ __forceinline__ unsigned short f32_to_bf16(float f) {
  unsigned u = __builtin_bit_cast(unsigned, f);
  u += 0x7fffu + ((u >> 16) & 1u);   // round-to-nearest-even
  return (unsigned short)(u >> 16);
}
__device__ __forceinline__ float wave_reduce_sum(float v) {
#pragma unroll
  for (int off = 32; off > 0; off >>= 1) v += __shfl_xor(v, off);
  return v;
}
__device__ __forceinline__ void gload_lds16(const void* g, void* l) {
  __builtin_amdgcn_global_load_lds(
      (const __attribute__((address_space(1))) unsigned int*)g,
      (__attribute__((address_space(3))) unsigned int*)l, 16, 0, 0);
}

// ---- style: style[mat][b][f] = s[b,:].aff_w[f,:] + aff_b[f]; wave=(mat,f), b-loop inside
__global__ void style_kernel(const float* __restrict__ s,
                             const float* __restrict__ kaw, const float* __restrict__ kab,
                             const float* __restrict__ oaw, const float* __restrict__ oab,
                             float* __restrict__ style_k, float* __restrict__ style_o) {
  const int gw = (int)((blockIdx.x * blockDim.x + threadIdx.x) >> 6);  // 0..2047
  const int lane = threadIdx.x & 63;
  const int mat = gw >> 10;
  const int f = gw & 1023;
  const float4* awv = (const float4*)((mat ? oaw : kaw) + (size_t)f * 512 + lane * 8);
  const float4 a0 = awv[0], a1 = awv[1];
  const float bias = (mat ? oab : kab)[f];
  float* dst = (mat ? style_o : style_k);
#pragma unroll
  for (int b = 0; b < 8; ++b) {
    const float4* sv = (const float4*)(s + b * 512 + lane * 8);
    const float4 s0 = sv[0], s1 = sv[1];
    float acc = a0.x * s0.x + a0.y * s0.y + a0.z * s0.z + a0.w * s0.w +
                a1.x * s1.x + a1.y * s1.y + a1.z * s1.z + a1.w * s1.w;
    acc = wave_reduce_sum(acc);
    if (lane == 0) dst[b * 1024 + f] = acc + bias;
  }
}

// ---- fused prep: blocks 0..511 wprep (demod + w->bf16), blocks 512.. xmod (x*style_k -> bf16)
__global__ void prep_kernel(const float* __restrict__ kw, const float* __restrict__ ow,
                            const float* __restrict__ style_k, const float* __restrict__ style_o,
                            float* __restrict__ dmk, float* __restrict__ dmo,
                            unsigned short* __restrict__ wkb, unsigned short* __restrict__ wob,
                            const float* __restrict__ x, unsigned short* __restrict__ xmod) {
  if (blockIdx.x < 512) {
    const int gw = (int)((blockIdx.x * blockDim.x + threadIdx.x) >> 6);  // 0..2047
    const int lane = threadIdx.x & 63;
    const int mat = gw >> 10;
    const int o = gw & 1023;
    const float* wrow = (mat ? ow : kw) + (size_t)o * 1024 + lane * 16;
    float w[16];
#pragma unroll
    for (int j = 0; j < 4; ++j) {
      const float4 t = ((const float4*)wrow)[j];
      w[j * 4 + 0] = t.x; w[j * 4 + 1] = t.y; w[j * 4 + 2] = t.z; w[j * 4 + 3] = t.w;
    }
    const float* stb = mat ? style_o : style_k;
    float* dm = mat ? dmo : dmk;
#pragma unroll
    for (int b = 0; b < 8; ++b) {
      const float4* sv = (const float4*)(stb + b * 1024 + lane * 16);
      float ss = 0.f;
#pragma unroll
      for (int j = 0; j < 4; ++j) {
        const float4 t = sv[j];
        const float v0 = w[j * 4 + 0] * t.x, v1 = w[j * 4 + 1] * t.y;
        const float v2 = w[j * 4 + 2] * t.z, v3 = w[j * 4 + 3] * t.w;
        ss += v0 * v0 + v1 * v1 + v2 * v2 + v3 * v3;
      }
      ss = wave_reduce_sum(ss);
      if (lane == 0) dm[b * 1024 + o] = rsqrtf(ss + 1e-8f);
    }
    unsigned short* wb = (mat ? wob : wkb) + (size_t)o * 1024 + lane * 16;
    ushort8 p0, p1;
#pragma unroll
    for (int t = 0; t < 8; ++t) { p0[t] = f32_to_bf16(w[t]); p1[t] = f32_to_bf16(w[8 + t]); }
    *(ushort8*)wb = p0;
    *(ushort8*)(wb + 8) = p1;
  } else {
    const int bid2 = blockIdx.x - 512;     // 0..4095
    const int b = bid2 & 7;                // batch == XCD
    const int j = bid2 >> 3;               // 0..511 within batch
    const int i8l = j * 256 + threadIdx.x; // 0..131071 (x8 elems) within batch
    const size_t i8 = ((size_t)b << 17) + i8l;
    const size_t base = i8 * 8;
    const int i0 = (int)(base & 1023);
    const float4* src = (const float4*)(x + base);
    const float4 a = src[0];
    const float4 b4 = src[1];
    const float4* st = (const float4*)(style_k + b * 1024 + i0);
    const float4 t0 = st[0], t1 = st[1];
    ushort8 w;
    w[0] = f32_to_bf16(a.x * t0.x); w[1] = f32_to_bf16(a.y * t0.y);
    w[2] = f32_to_bf16(a.z * t0.z); w[3] = f32_to_bf16(a.w * t0.w);
    w[4] = f32_to_bf16(b4.x * t1.x); w[5] = f32_to_bf16(b4.y * t1.y);
    w[6] = f32_to_bf16(b4.z * t1.z); w[7] = f32_to_bf16(b4.w * t1.w);
    ((ushort8*)xmod)[i8] = w;
  }
}

// ---- batched-A, SHARED-B GEMM: C[b] = A[b] (1024xK) * Bw (1024xK)^T, epi: *dm[b,col] + bias
// BM=128, BN=128, BK=64, 8 waves (512 thr, 2x4 wave grid, wave tile 64x32),
// 64 KB LDS -> 2 blocks/CU = 16 waves/CU = 4 waves/SIMD (vs 2 in the 4-wave
// config) for latency hiding across the per-tile barrier drain.
// Depth-2 counted-vmcnt pipeline (4 loads/thread/tile -> vmcnt(4)), XOR swizzle.
// 1D grid 512: bz = id&7 pins each batch to one XCD (A 2MB + W 2MB = L2-resident).
template <bool OUT_BF16>
__launch_bounds__(512, 2)
__global__ void gemm_bt(const unsigned short* __restrict__ A,
                        const unsigned short* __restrict__ Bw,
                        const float* __restrict__ dm,
                        const float* __restrict__ bias,
                        void* __restrict__ C) {
  constexpr int Kd = 1024;
  constexpr int NT = Kd / 64;  // 16 K-tiles
  __shared__ unsigned short As[2 * 128 * 64];  // 32 KB
  __shared__ unsigned short Bs[2 * 128 * 64];  // 32 KB
  const int id = blockIdx.x;
  const int bz = id & 7;            // batch == XCD (round-robin dispatch)
  const int chunk = id >> 3;        // 0..63
  const int tileN = (chunk & 7) << 7;
  const int tileM = (chunk >> 3) << 7;
  const int tid = threadIdx.x;
  const int wid = tid >> 6, lane = tid & 63;
  const int wr = wid >> 2, wc = wid & 3;       // 2x4 wave grid; wave tile 64x32
  const int frow = lane & 15, hi = lane >> 4;
  const unsigned short* Ab = A + ((size_t)bz * 1024 + tileM) * Kd;
  const unsigned short* Bb = Bw + (size_t)tileN * Kd;   // shared weight

  f32x4 acc[4][2];
#pragma unroll
  for (int m = 0; m < 4; ++m)
#pragma unroll
    for (int n = 0; n < 2; ++n) acc[m][n] = (f32x4){0.f, 0.f, 0.f, 0.f};

  const int wq = wid << 6;  // wave-uniform chunk base (8 waves x 64 chunks = 512)

  auto stage = [&](int buf, int kt) {
    // each array: 1024 chunks of 16B; 512 threads -> 2 chunks/thread/array
#pragma unroll
    for (int j = 0; j < 2; ++j) {
      const int qb = j * 512 + wq;
      const int q = qb + lane;
      const int r = q >> 3;
      const int sc = (q & 7) ^ (r & 7);
      gload_lds16(Ab + (size_t)r * Kd + kt * 64 + sc * 8, (void*)&As[buf * 8192 + qb * 8]);
    }
#pragma unroll
    for (int j = 0; j < 2; ++j) {
      const int qb = j * 512 + wq;
      const int q = qb + lane;
      const int r = q >> 3;
      const int sc = (q & 7) ^ (r & 7);
      gload_lds16(Bb + (size_t)r * Kd + kt * 64 + sc * 8, (void*)&Bs[buf * 8192 + qb * 8]);
    }
  };

  stage(0, 0);
  stage(1, 1);

  for (int kt = 0; kt < NT; ++kt) {
    const int buf = kt & 1;
    if (kt + 1 < NT) asm volatile("s_waitcnt vmcnt(4)" ::: "memory");
    else             asm volatile("s_waitcnt vmcnt(0)" ::: "memory");
    __builtin_amdgcn_s_barrier();
    asm volatile("" ::: "memory");

    bf16x8 av[4][2], bv[2][2];
#pragma unroll
    for (int m = 0; m < 4; ++m) {
      const int row = (wr << 6) + (m << 4) + frow;
#pragma unroll
      for (int ks = 0; ks < 2; ++ks) {
        const int ch = ((ks << 2) + hi) ^ (row & 7);
        av[m][ks] = *(const bf16x8*)&As[buf * 8192 + row * 64 + ch * 8];
      }
    }
#pragma unroll
    for (int n = 0; n < 2; ++n) {
      const int row = (wc << 5) + (n << 4) + frow;
#pragma unroll
      for (int ks = 0; ks < 2; ++ks) {
        const int ch = ((ks << 2) + hi) ^ (row & 7);
        bv[n][ks] = *(const bf16x8*)&Bs[buf * 8192 + row * 64 + ch * 8];
      }
    }
#pragma unroll
    for (int ks = 0; ks < 2; ++ks)
#pragma unroll
      for (int m = 0; m < 4; ++m)
#pragma unroll
        for (int n = 0; n < 2; ++n)
          acc[m][n] = __builtin_amdgcn_mfma_f32_16x16x32_bf16(av[m][ks], bv[n][ks],
                                                              acc[m][n], 0, 0, 0);
    asm volatile("s_waitcnt lgkmcnt(0)" ::: "memory");
    __builtin_amdgcn_s_barrier();
    asm volatile("" ::: "memory");
    if (kt + 2 < NT) stage(buf, kt + 2);
  }

  const int crow0 = tileM + (wr << 6);
  const int ccol0 = tileN + (wc << 5);
#pragma unroll
  for (int n = 0; n < 2; ++n) {
    const int col = ccol0 + n * 16 + frow;
    const float dm_c = dm[bz * 1024 + col];
    const float bias_c = bias[col];
#pragma unroll
    for (int m = 0; m < 4; ++m) {
#pragma unroll
      for (int i = 0; i < 4; ++i) {
        const int row = crow0 + m * 16 + (hi << 2) + i;
        const float v = acc[m][n][i] * dm_c + bias_c;
        const size_t idx = ((size_t)bz * 1024 + row) * 1024 + col;
        if constexpr (OUT_BF16)
          ((unsigned short*)C)[idx] = f32_to_bf16(v);
        else
          ((float*)C)[idx] = v;
      }
    }
  }
}

// ---- per-token 16x16 head-mix attention via MFMA (1 wave / token)
__global__ void attn_kernel(const unsigned short* __restrict__ kx,
                            const float* __restrict__ style_o,
                            unsigned short* __restrict__ att) {
  __shared__ __align__(16) unsigned short KXt[4][64][17];  // [d][j] transposed
  __shared__ __align__(16) unsigned short Pl[4][16][24];
  __shared__ __align__(16) float Ol[4][16][68];            // [m'][d]
  const int w = threadIdx.x >> 6, lane = threadIdx.x & 63;
  const int bz = blockIdx.x & 7;                 // batch == XCD
  const int tg = blockIdx.x >> 3;                // 0..255 token-group in batch
  const int token = (bz << 10) + (tg << 2) + w;
  const int m = lane & 15, hi = lane >> 4;
  const unsigned short* src = kx + (size_t)token * 1024;

  ushort8 af0 = *(const ushort8*)(src + m * 64 + hi * 8);
  ushort8 af1 = *(const ushort8*)(src + m * 64 + 32 + hi * 8);
#pragma unroll
  for (int t = 0; t < 8; ++t) {
    KXt[w][hi * 8 + t][m] = af0[t];
    KXt[w][32 + hi * 8 + t][m] = af1[t];
  }

  f32x4 s = {0.f, 0.f, 0.f, 0.f};
  s = __builtin_amdgcn_mfma_f32_16x16x32_bf16(__builtin_bit_cast(bf16x8, af0),
                                              __builtin_bit_cast(bf16x8, af0), s, 0, 0, 0);
  s = __builtin_amdgcn_mfma_f32_16x16x32_bf16(__builtin_bit_cast(bf16x8, af1),
                                              __builtin_bit_cast(bf16x8, af1), s, 0, 0, 0);
  float v[4], mx[4], sum[4];
#pragma unroll
  for (int i = 0; i < 4; ++i) { v[i] = s[i] * 0.125f; mx[i] = v[i]; }
#pragma unroll
  for (int off = 1; off <= 8; off <<= 1)
#pragma unroll
    for (int i = 0; i < 4; ++i) mx[i] = fmaxf(mx[i], __shfl_xor(mx[i], off));
#pragma unroll
  for (int i = 0; i < 4; ++i) { v[i] = __expf(v[i] - mx[i]); sum[i] = v[i]; }
#pragma unroll
  for (int off = 1; off <= 8; off <<= 1)
#pragma unroll
    for (int i = 0; i < 4; ++i) sum[i] += __shfl_xor(sum[i], off);
#pragma unroll
  for (int i = 0; i < 4; ++i) Pl[w][4 * hi + i][m] = f32_to_bf16(v[i] / sum[i]);

  asm volatile("s_waitcnt lgkmcnt(0)" ::: "memory");
  __builtin_amdgcn_sched_barrier(0);

  const int jb = (hi & 1) << 3;
  bf16x8 pa;
  if (hi < 2) pa = *(const bf16x8*)&Pl[w][m][jb];
  else        pa = (bf16x8){0, 0, 0, 0, 0, 0, 0, 0};
#pragma unroll
  for (int blk = 0; blk < 4; ++blk) {
    const bf16x8 bb = *(const bf16x8*)&KXt[w][blk * 16 + m][jb];
    f32x4 o = {0.f, 0.f, 0.f, 0.f};
    o = __builtin_amdgcn_mfma_f32_16x16x32_bf16(pa, bb, o, 0, 0, 0);
#pragma unroll
    for (int i = 0; i < 4; ++i) Ol[w][4 * hi + i][blk * 16 + m] = o[i];
  }
  asm volatile("s_waitcnt lgkmcnt(0)" ::: "memory");
  __builtin_amdgcn_sched_barrier(0);

  const int mr = lane >> 2, d0 = (lane & 3) << 4;
  const int fbase = mr * 64 + d0;
  const float* so = style_o + (size_t)bz * 1024 + fbase;
  const float4 s0v = ((const float4*)so)[0];
  const float4 s1v = ((const float4*)so)[1];
  const float4 s2v = ((const float4*)so)[2];
  const float4 s3v = ((const float4*)so)[3];
  float ov[16];
#pragma unroll
  for (int t = 0; t < 16; ++t) ov[t] = Ol[w][mr][d0 + t];
  ov[0] *= s0v.x;  ov[1] *= s0v.y;  ov[2] *= s0v.z;  ov[3] *= s0v.w;
  ov[4] *= s1v.x;  ov[5] *= s1v.y;  ov[6] *= s1v.z;  ov[7] *= s1v.w;
  ov[8] *= s2v.x;  ov[9] *= s2v.y;  ov[10] *= s2v.z; ov[11] *= s2v.w;
  ov[12] *= s3v.x; ov[13] *= s3v.y; ov[14] *= s3v.z; ov[15] *= s3v.w;
  ushort8 w0, w1;
#pragma unroll
  for (int t = 0; t < 8; ++t) { w0[t] = f32_to_bf16(ov[t]); w1[t] = f32_to_bf16(ov[8 + t]); }
  unsigned short* dst = att + (size_t)token * 1024 + fbase;
  *(ushort8*)dst = w0;
  *(ushort8*)(dst + 8) = w1;
}

extern "C" void kernel_launch(void* const* d_in, const int* in_sizes, int n_in,
                              void* d_out, int out_size, void* d_ws, size_t ws_size,
                              hipStream_t stream) {
  const float* x     = (const float*)d_in[0];
  const float* s     = (const float*)d_in[1];
  const float* k_aff_w = (const float*)d_in[2];
  const float* k_aff_b = (const float*)d_in[3];
  const float* k_w   = (const float*)d_in[4];
  const float* k_b   = (const float*)d_in[5];
  const float* o_aff_w = (const float*)d_in[6];
  const float* o_aff_b = (const float*)d_in[7];
  const float* o_w   = (const float*)d_in[8];
  const float* o_b   = (const float*)d_in[9];
  float* out = (float*)d_out;

  char* ws = (char*)d_ws;
  float* style_k = (float*)(ws);                                  // 32 KB
  float* style_o = (float*)(ws + (32 << 10));                     // 32 KB
  float* dmk     = (float*)(ws + (64 << 10));                     // 32 KB
  float* dmo     = (float*)(ws + (96 << 10));                     // 32 KB
  unsigned short* wkb  = (unsigned short*)(ws + ((size_t)1 << 20));   // 2 MB
  unsigned short* wob  = (unsigned short*)(ws + ((size_t)3 << 20));   // 2 MB
  unsigned short* xmod = (unsigned short*)(ws + ((size_t)8 << 20));   // 16 MB
  unsigned short* kxb  = (unsigned short*)(ws + ((size_t)24 << 20));  // 16 MB
  unsigned short* attb = (unsigned short*)(ws + ((size_t)40 << 20));  // 16 MB

  style_kernel<<<512, 256, 0, stream>>>(s, k_aff_w, k_aff_b, o_aff_w, o_aff_b,
                                        style_k, style_o);
  prep_kernel<<<4608, 256, 0, stream>>>(k_w, o_w, style_k, style_o,
                                        dmk, dmo, wkb, wob, x, xmod);
  gemm_bt<true><<<512, 512, 0, stream>>>(xmod, wkb, dmk, k_b, (void*)kxb);
  attn_kernel<<<2048, 256, 0, stream>>>(kxb, style_o, attb);
  gemm_bt<false><<<512, 512, 0, stream>>>(attb, wob, dmo, o_b, (void*)out);
}

// Round 14
// 77.986 us; speedup vs baseline: 1.0029x; 1.0029x over previous
//
#include <hip/hip_runtime.h>

typedef __attribute__((ext_vector_type(4))) float f32x4;
typedef __attribute__((ext_vector_type(8))) __bf16 bf16x8;
typedef __attribute__((ext_vector_type(8))) unsigned short ushort8;

__device__ __forceinline__ unsigned short f32_to_bf16(float f) {
  unsigned u = __builtin_bit_cast(unsigned, f);
  u += 0x7fffu + ((u >> 16) & 1u);   // round-to-nearest-even
  return (unsigned short)(u >> 16);
}
__device__ __forceinline__ float wave_reduce_sum(float v) {
#pragma unroll
  for (int off = 32; off > 0; off >>= 1) v += __shfl_xor(v, off);
  return v;
}
__device__ __forceinline__ void gload_lds16(const void* g, void* l) {
  __builtin_amdgcn_global_load_lds(
      (const __attribute__((address_space(1))) unsigned int*)g,
      (__attribute__((address_space(3))) unsigned int*)l, 16, 0, 0);
}

// ---- style: style[mat][b][f] = s[b,:].aff_w[f,:] + aff_b[f]; wave=(mat,f), b-loop inside
__global__ void style_kernel(const float* __restrict__ s,
                             const float* __restrict__ kaw, const float* __restrict__ kab,
                             const float* __restrict__ oaw, const float* __restrict__ oab,
                             float* __restrict__ style_k, float* __restrict__ style_o) {
  const int gw = (int)((blockIdx.x * blockDim.x + threadIdx.x) >> 6);  // 0..2047
  const int lane = threadIdx.x & 63;
  const int mat = gw >> 10;
  const int f = gw & 1023;
  const float4* awv = (const float4*)((mat ? oaw : kaw) + (size_t)f * 512 + lane * 8);
  const float4 a0 = awv[0], a1 = awv[1];
  const float bias = (mat ? oab : kab)[f];
  float* dst = (mat ? style_o : style_k);
#pragma unroll
  for (int b = 0; b < 8; ++b) {
    const float4* sv = (const float4*)(s + b * 512 + lane * 8);
    const float4 s0 = sv[0], s1 = sv[1];
    float acc = a0.x * s0.x + a0.y * s0.y + a0.z * s0.z + a0.w * s0.w +
                a1.x * s1.x + a1.y * s1.y + a1.z * s1.z + a1.w * s1.w;
    acc = wave_reduce_sum(acc);
    if (lane == 0) dst[b * 1024 + f] = acc + bias;
  }
}

// ---- fused prep: blocks 0..511 wprep (demod + w->bf16), blocks 512.. xmod (x*style_k -> bf16)
__global__ void prep_kernel(const float* __restrict__ kw, const float* __restrict__ ow,
                            const float* __restrict__ style_k, const float* __restrict__ style_o,
                            float* __restrict__ dmk, float* __restrict__ dmo,
                            unsigned short* __restrict__ wkb, unsigned short* __restrict__ wob,
                            const float* __restrict__ x, unsigned short* __restrict__ xmod) {
  if (blockIdx.x < 512) {
    const int gw = (int)((blockIdx.x * blockDim.x + threadIdx.x) >> 6);  // 0..2047
    const int lane = threadIdx.x & 63;
    const int mat = gw >> 10;
    const int o = gw & 1023;
    const float* wrow = (mat ? ow : kw) + (size_t)o * 1024 + lane * 16;
    float w[16];
#pragma unroll
    for (int j = 0; j < 4; ++j) {
      const float4 t = ((const float4*)wrow)[j];
      w[j * 4 + 0] = t.x; w[j * 4 + 1] = t.y; w[j * 4 + 2] = t.z; w[j * 4 + 3] = t.w;
    }
    const float* stb = mat ? style_o : style_k;
    float* dm = mat ? dmo : dmk;
#pragma unroll
    for (int b = 0; b < 8; ++b) {
      const float4* sv = (const float4*)(stb + b * 1024 + lane * 16);
      float ss = 0.f;
#pragma unroll
      for (int j = 0; j < 4; ++j) {
        const float4 t = sv[j];
        const float v0 = w[j * 4 + 0] * t.x, v1 = w[j * 4 + 1] * t.y;
        const float v2 = w[j * 4 + 2] * t.z, v3 = w[j * 4 + 3] * t.w;
        ss += v0 * v0 + v1 * v1 + v2 * v2 + v3 * v3;
      }
      ss = wave_reduce_sum(ss);
      if (lane == 0) dm[b * 1024 + o] = rsqrtf(ss + 1e-8f);
    }
    unsigned short* wb = (mat ? wob : wkb) + (size_t)o * 1024 + lane * 16;
    ushort8 p0, p1;
#pragma unroll
    for (int t = 0; t < 8; ++t) { p0[t] = f32_to_bf16(w[t]); p1[t] = f32_to_bf16(w[8 + t]); }
    *(ushort8*)wb = p0;
    *(ushort8*)(wb + 8) = p1;
  } else {
    const int bid2 = blockIdx.x - 512;     // 0..4095
    const int b = bid2 & 7;                // batch == XCD
    const int j = bid2 >> 3;               // 0..511 within batch
    const int i8l = j * 256 + threadIdx.x; // 0..131071 (x8 elems) within batch
    const size_t i8 = ((size_t)b << 17) + i8l;
    const size_t base = i8 * 8;
    const int i0 = (int)(base & 1023);
    const float4* src = (const float4*)(x + base);
    const float4 a = src[0];
    const float4 b4 = src[1];
    const float4* st = (const float4*)(style_k + b * 1024 + i0);
    const float4 t0 = st[0], t1 = st[1];
    ushort8 w;
    w[0] = f32_to_bf16(a.x * t0.x); w[1] = f32_to_bf16(a.y * t0.y);
    w[2] = f32_to_bf16(a.z * t0.z); w[3] = f32_to_bf16(a.w * t0.w);
    w[4] = f32_to_bf16(b4.x * t1.x); w[5] = f32_to_bf16(b4.y * t1.y);
    w[6] = f32_to_bf16(b4.z * t1.z); w[7] = f32_to_bf16(b4.w * t1.w);
    ((ushort8*)xmod)[i8] = w;
  }
}

// ---- batched-A, SHARED-B GEMM: C[b] = A[b] (1024xK) * Bw (1024xK)^T, epi: *dm[b,col] + bias
// BM=128, BN=128, BK=64, 4 waves (256 thr, 2x2), 64 KB LDS -> 2 blocks/CU.
// T3-minimum single-barrier schedule (catalog-verbatim): per K-tile,
//   STAGE(buf^1, kt+1) issued FIRST, then ds_read+MFMA from buf, then
//   lgkmcnt(0) (reads of buf drained) + vmcnt(0) (next tile staged) + barrier.
// Race-free: all waves' reads of buf complete at the barrier, so iter kt+1's
// stage into buf is safe; vmcnt(0)+barrier certifies tile kt+1 globally.
// 1D grid 512: bz = id&7 pins each batch to one XCD (A 2MB + W 2MB = L2-resident).
template <bool OUT_BF16>
__launch_bounds__(256, 2)
__global__ void gemm_bt(const unsigned short* __restrict__ A,
                        const unsigned short* __restrict__ Bw,
                        const float* __restrict__ dm,
                        const float* __restrict__ bias,
                        void* __restrict__ C) {
  constexpr int Kd = 1024;
  constexpr int NT = Kd / 64;  // 16 K-tiles
  __shared__ unsigned short As[2 * 128 * 64];  // 32 KB
  __shared__ unsigned short Bs[2 * 128 * 64];  // 32 KB
  const int id = blockIdx.x;
  const int bz = id & 7;            // batch == XCD (round-robin dispatch)
  const int chunk = id >> 3;        // 0..63
  const int tileN = (chunk & 7) << 7;
  const int tileM = (chunk >> 3) << 7;
  const int tid = threadIdx.x;
  const int wid = tid >> 6, lane = tid & 63;
  const int wr = wid >> 1, wc = wid & 1;
  const int frow = lane & 15, hi = lane >> 4;
  const unsigned short* Ab = A + ((size_t)bz * 1024 + tileM) * Kd;
  const unsigned short* Bb = Bw + (size_t)tileN * Kd;   // shared weight

  f32x4 acc[4][4];
#pragma unroll
  for (int m = 0; m < 4; ++m)
#pragma unroll
    for (int n = 0; n < 4; ++n) acc[m][n] = (f32x4){0.f, 0.f, 0.f, 0.f};

  const int wq = wid << 6;  // wave-uniform chunk base within a 256-chunk group

  auto stage = [&](int buf, int kt) {
    // each array: 1024 chunks of 16B; 256 threads -> 4 chunks/thread/array
#pragma unroll
    for (int j = 0; j < 4; ++j) {
      const int qb = j * 256 + wq;
      const int q = qb + lane;
      const int r = q >> 3;
      const int sc = (q & 7) ^ (r & 7);
      gload_lds16(Ab + (size_t)r * Kd + kt * 64 + sc * 8, (void*)&As[buf * 8192 + qb * 8]);
    }
#pragma unroll
    for (int j = 0; j < 4; ++j) {
      const int qb = j * 256 + wq;
      const int q = qb + lane;
      const int r = q >> 3;
      const int sc = (q & 7) ^ (r & 7);
      gload_lds16(Bb + (size_t)r * Kd + kt * 64 + sc * 8, (void*)&Bs[buf * 8192 + qb * 8]);
    }
  };

  // prologue: tile 0 staged and visible
  stage(0, 0);
  asm volatile("s_waitcnt vmcnt(0)" ::: "memory");
  __builtin_amdgcn_s_barrier();
  asm volatile("" ::: "memory");

  for (int kt = 0; kt < NT; ++kt) {
    const int buf = kt & 1;
    // issue next tile's stage FIRST (into the other buffer)
    if (kt + 1 < NT) stage(buf ^ 1, kt + 1);

    bf16x8 av[4][2], bv[4][2];
#pragma unroll
    for (int m = 0; m < 4; ++m) {
      const int row = (wr << 6) + (m << 4) + frow;
#pragma unroll
      for (int ks = 0; ks < 2; ++ks) {
        const int ch = ((ks << 2) + hi) ^ (row & 7);
        av[m][ks] = *(const bf16x8*)&As[buf * 8192 + row * 64 + ch * 8];
      }
    }
#pragma unroll
    for (int n = 0; n < 4; ++n) {
      const int row = (wc << 6) + (n << 4) + frow;
#pragma unroll
      for (int ks = 0; ks < 2; ++ks) {
        const int ch = ((ks << 2) + hi) ^ (row & 7);
        bv[n][ks] = *(const bf16x8*)&Bs[buf * 8192 + row * 64 + ch * 8];
      }
    }
    // reads of buf drained before MFMA (and thus before the barrier below)
    asm volatile("s_waitcnt lgkmcnt(0)" ::: "memory");
    __builtin_amdgcn_sched_barrier(0);
#pragma unroll
    for (int ks = 0; ks < 2; ++ks)
#pragma unroll
      for (int m = 0; m < 4; ++m)
#pragma unroll
        for (int n = 0; n < 4; ++n)
          acc[m][n] = __builtin_amdgcn_mfma_f32_16x16x32_bf16(av[m][ks], bv[n][ks],
                                                              acc[m][n], 0, 0, 0);
    // single barrier per tile: next tile staged + all reads of buf done
    asm volatile("s_waitcnt vmcnt(0)" ::: "memory");
    __builtin_amdgcn_s_barrier();
    asm volatile("" ::: "memory");
  }

  const int crow0 = tileM + (wr << 6);
  const int ccol0 = tileN + (wc << 6);
#pragma unroll
  for (int n = 0; n < 4; ++n) {
    const int col = ccol0 + n * 16 + frow;
    const float dm_c = dm[bz * 1024 + col];
    const float bias_c = bias[col];
#pragma unroll
    for (int m = 0; m < 4; ++m) {
#pragma unroll
      for (int i = 0; i < 4; ++i) {
        const int row = crow0 + m * 16 + (hi << 2) + i;
        const float v = acc[m][n][i] * dm_c + bias_c;
        const size_t idx = ((size_t)bz * 1024 + row) * 1024 + col;
        if constexpr (OUT_BF16)
          ((unsigned short*)C)[idx] = f32_to_bf16(v);
        else
          ((float*)C)[idx] = v;
      }
    }
  }
}

// ---- per-token 16x16 head-mix attention via MFMA (1 wave / token)
__global__ void attn_kernel(const unsigned short* __restrict__ kx,
                            const float* __restrict__ style_o,
                            unsigned short* __restrict__ att) {
  __shared__ __align__(16) unsigned short KXt[4][64][17];  // [d][j] transposed
  __shared__ __align__(16) unsigned short Pl[4][16][24];
  __shared__ __align__(16) float Ol[4][16][68];            // [m'][d]
  const int w = threadIdx.x >> 6, lane = threadIdx.x & 63;
  const int bz = blockIdx.x & 7;                 // batch == XCD
  const int tg = blockIdx.x >> 3;                // 0..255 token-group in batch
  const int token = (bz << 10) + (tg << 2) + w;
  const int m = lane & 15, hi = lane >> 4;
  const unsigned short* src = kx + (size_t)token * 1024;

  ushort8 af0 = *(const ushort8*)(src + m * 64 + hi * 8);
  ushort8 af1 = *(const ushort8*)(src + m * 64 + 32 + hi * 8);
#pragma unroll
  for (int t = 0; t < 8; ++t) {
    KXt[w][hi * 8 + t][m] = af0[t];
    KXt[w][32 + hi * 8 + t][m] = af1[t];
  }

  f32x4 s = {0.f, 0.f, 0.f, 0.f};
  s = __builtin_amdgcn_mfma_f32_16x16x32_bf16(__builtin_bit_cast(bf16x8, af0),
                                              __builtin_bit_cast(bf16x8, af0), s, 0, 0, 0);
  s = __builtin_amdgcn_mfma_f32_16x16x32_bf16(__builtin_bit_cast(bf16x8, af1),
                                              __builtin_bit_cast(bf16x8, af1), s, 0, 0, 0);
  float v[4], mx[4], sum[4];
#pragma unroll
  for (int i = 0; i < 4; ++i) { v[i] = s[i] * 0.125f; mx[i] = v[i]; }
#pragma unroll
  for (int off = 1; off <= 8; off <<= 1)
#pragma unroll
    for (int i = 0; i < 4; ++i) mx[i] = fmaxf(mx[i], __shfl_xor(mx[i], off));
#pragma unroll
  for (int i = 0; i < 4; ++i) { v[i] = __expf(v[i] - mx[i]); sum[i] = v[i]; }
#pragma unroll
  for (int off = 1; off <= 8; off <<= 1)
#pragma unroll
    for (int i = 0; i < 4; ++i) sum[i] += __shfl_xor(sum[i], off);
#pragma unroll
  for (int i = 0; i < 4; ++i) Pl[w][4 * hi + i][m] = f32_to_bf16(v[i] / sum[i]);

  asm volatile("s_waitcnt lgkmcnt(0)" ::: "memory");
  __builtin_amdgcn_sched_barrier(0);

  const int jb = (hi & 1) << 3;
  bf16x8 pa;
  if (hi < 2) pa = *(const bf16x8*)&Pl[w][m][jb];
  else        pa = (bf16x8){0, 0, 0, 0, 0, 0, 0, 0};
#pragma unroll
  for (int blk = 0; blk < 4; ++blk) {
    const bf16x8 bb = *(const bf16x8*)&KXt[w][blk * 16 + m][jb];
    f32x4 o = {0.f, 0.f, 0.f, 0.f};
    o = __builtin_amdgcn_mfma_f32_16x16x32_bf16(pa, bb, o, 0, 0, 0);
#pragma unroll
    for (int i = 0; i < 4; ++i) Ol[w][4 * hi + i][blk * 16 + m] = o[i];
  }
  asm volatile("s_waitcnt lgkmcnt(0)" ::: "memory");
  __builtin_amdgcn_sched_barrier(0);

  const int mr = lane >> 2, d0 = (lane & 3) << 4;
  const int fbase = mr * 64 + d0;
  const float* so = style_o + (size_t)bz * 1024 + fbase;
  const float4 s0v = ((const float4*)so)[0];
  const float4 s1v = ((const float4*)so)[1];
  const float4 s2v = ((const float4*)so)[2];
  const float4 s3v = ((const float4*)so)[3];
  float ov[16];
#pragma unroll
  for (int t = 0; t < 16; ++t) ov[t] = Ol[w][mr][d0 + t];
  ov[0] *= s0v.x;  ov[1] *= s0v.y;  ov[2] *= s0v.z;  ov[3] *= s0v.w;
  ov[4] *= s1v.x;  ov[5] *= s1v.y;  ov[6] *= s1v.z;  ov[7] *= s1v.w;
  ov[8] *= s2v.x;  ov[9] *= s2v.y;  ov[10] *= s2v.z; ov[11] *= s2v.w;
  ov[12] *= s3v.x; ov[13] *= s3v.y; ov[14] *= s3v.z; ov[15] *= s3v.w;
  ushort8 w0, w1;
#pragma unroll
  for (int t = 0; t < 8; ++t) { w0[t] = f32_to_bf16(ov[t]); w1[t] = f32_to_bf16(ov[8 + t]); }
  unsigned short* dst = att + (size_t)token * 1024 + fbase;
  *(ushort8*)dst = w0;
  *(ushort8*)(dst + 8) = w1;
}

extern "C" void kernel_launch(void* const* d_in, const int* in_sizes, int n_in,
                              void* d_out, int out_size, void* d_ws, size_t ws_size,
                              hipStream_t stream) {
  const float* x     = (const float*)d_in[0];
  const float* s     = (const float*)d_in[1];
  const float* k_aff_w = (const float*)d_in[2];
  const float* k_aff_b = (const float*)d_in[3];
  const float* k_w   = (const float*)d_in[4];
  const float* k_b   = (const float*)d_in[5];
  const float* o_aff_w = (const float*)d_in[6];
  const float* o_aff_b = (const float*)d_in[7];
  const float* o_w   = (const float*)d_in[8];
  const float* o_b   = (const float*)d_in[9];
  float* out = (float*)d_out;

  char* ws = (char*)d_ws;
  float* style_k = (float*)(ws);                                  // 32 KB
  float* style_o = (float*)(ws + (32 << 10));                     // 32 KB
  float* dmk     = (float*)(ws + (64 << 10));                     // 32 KB
  float* dmo     = (float*)(ws + (96 << 10));                     // 32 KB
  unsigned short* wkb  = (unsigned short*)(ws + ((size_t)1 << 20));   // 2 MB
  unsigned short* wob  = (unsigned short*)(ws + ((size_t)3 << 20));   // 2 MB
  unsigned short* xmod = (unsigned short*)(ws + ((size_t)8 << 20));   // 16 MB
  unsigned short* kxb  = (unsigned short*)(ws + ((size_t)24 << 20));  // 16 MB
  unsigned short* attb = (unsigned short*)(ws + ((size_t)40 << 20));  // 16 MB

  style_kernel<<<512, 256, 0, stream>>>(s, k_aff_w, k_aff_b, o_aff_w, o_aff_b,
                                        style_k, style_o);
  prep_kernel<<<4608, 256, 0, stream>>>(k_w, o_w, style_k, style_o,
                                        dmk, dmo, wkb, wob, x, xmod);
  gemm_bt<true><<<512, 256, 0, stream>>>(xmod, wkb, dmk, k_b, (void*)kxb);
  attn_kernel<<<2048, 256, 0, stream>>>(kxb, style_o, attb);
  gemm_bt<false><<<512, 256, 0, stream>>>(attb, wob, dmo, o_b, (void*)out);
}

// Round 15
// 74.935 us; speedup vs baseline: 1.0438x; 1.0407x over previous
//
#include <hip/hip_runtime.h>

typedef __attribute__((ext_vector_type(4))) float f32x4;
typedef __attribute__((ext_vector_type(8))) __bf16 bf16x8;
typedef __attribute__((ext_vector_type(8))) unsigned short ushort8;

__device__ __forceinline__ unsigned short f32_to_bf16(float f) {
  unsigned u = __builtin_bit_cast(unsigned, f);
  u += 0x7fffu + ((u >> 16) & 1u);   // round-to-nearest-even
  return (unsigned short)(u >> 16);
}
__device__ __forceinline__ float wave_reduce_sum(float v) {
#pragma unroll
  for (int off = 32; off > 0; off >>= 1) v += __shfl_xor(v, off);
  return v;
}
__device__ __forceinline__ void gload_lds16(const void* g, void* l) {
  __builtin_amdgcn_global_load_lds(
      (const __attribute__((address_space(1))) unsigned int*)g,
      (__attribute__((address_space(3))) unsigned int*)l, 16, 0, 0);
}

// ---- style: style[mat][b][f] = s[b,:].aff_w[f,:] + aff_b[f]; wave=(mat,f), b-loop inside
__global__ void style_kernel(const float* __restrict__ s,
                             const float* __restrict__ kaw, const float* __restrict__ kab,
                             const float* __restrict__ oaw, const float* __restrict__ oab,
                             float* __restrict__ style_k, float* __restrict__ style_o) {
  const int gw = (int)((blockIdx.x * blockDim.x + threadIdx.x) >> 6);  // 0..2047
  const int lane = threadIdx.x & 63;
  const int mat = gw >> 10;
  const int f = gw & 1023;
  const float4* awv = (const float4*)((mat ? oaw : kaw) + (size_t)f * 512 + lane * 8);
  const float4 a0 = awv[0], a1 = awv[1];
  const float bias = (mat ? oab : kab)[f];
  float* dst = (mat ? style_o : style_k);
#pragma unroll
  for (int b = 0; b < 8; ++b) {
    const float4* sv = (const float4*)(s + b * 512 + lane * 8);
    const float4 s0 = sv[0], s1 = sv[1];
    float acc = a0.x * s0.x + a0.y * s0.y + a0.z * s0.z + a0.w * s0.w +
                a1.x * s1.x + a1.y * s1.y + a1.z * s1.z + a1.w * s1.w;
    acc = wave_reduce_sum(acc);
    if (lane == 0) dst[b * 1024 + f] = acc + bias;
  }
}

// ---- fused prep: blocks 0..511 wprep (demod + w->bf16), blocks 512.. xmod (x*style_k -> bf16)
// Cast section is XCD-pinned: batch = (id-512)&7 so xmod[b] lands in XCD b's L2,
// matching gemm1's batch->XCD pinning (cross-XCD L2s are not coherent/shared).
__global__ void prep_kernel(const float* __restrict__ kw, const float* __restrict__ ow,
                            const float* __restrict__ style_k, const float* __restrict__ style_o,
                            float* __restrict__ dmk, float* __restrict__ dmo,
                            unsigned short* __restrict__ wkb, unsigned short* __restrict__ wob,
                            const float* __restrict__ x, unsigned short* __restrict__ xmod) {
  if (blockIdx.x < 512) {
    const int gw = (int)((blockIdx.x * blockDim.x + threadIdx.x) >> 6);  // 0..2047
    const int lane = threadIdx.x & 63;
    const int mat = gw >> 10;
    const int o = gw & 1023;
    const float* wrow = (mat ? ow : kw) + (size_t)o * 1024 + lane * 16;
    float w[16];
#pragma unroll
    for (int j = 0; j < 4; ++j) {
      const float4 t = ((const float4*)wrow)[j];
      w[j * 4 + 0] = t.x; w[j * 4 + 1] = t.y; w[j * 4 + 2] = t.z; w[j * 4 + 3] = t.w;
    }
    const float* stb = mat ? style_o : style_k;
    float* dm = mat ? dmo : dmk;
#pragma unroll
    for (int b = 0; b < 8; ++b) {
      const float4* sv = (const float4*)(stb + b * 1024 + lane * 16);
      float ss = 0.f;
#pragma unroll
      for (int j = 0; j < 4; ++j) {
        const float4 t = sv[j];
        const float v0 = w[j * 4 + 0] * t.x, v1 = w[j * 4 + 1] * t.y;
        const float v2 = w[j * 4 + 2] * t.z, v3 = w[j * 4 + 3] * t.w;
        ss += v0 * v0 + v1 * v1 + v2 * v2 + v3 * v3;
      }
      ss = wave_reduce_sum(ss);
      if (lane == 0) dm[b * 1024 + o] = rsqrtf(ss + 1e-8f);
    }
    unsigned short* wb = (mat ? wob : wkb) + (size_t)o * 1024 + lane * 16;
    ushort8 p0, p1;
#pragma unroll
    for (int t = 0; t < 8; ++t) { p0[t] = f32_to_bf16(w[t]); p1[t] = f32_to_bf16(w[8 + t]); }
    *(ushort8*)wb = p0;
    *(ushort8*)(wb + 8) = p1;
  } else {
    const int bid2 = blockIdx.x - 512;     // 0..4095
    const int b = bid2 & 7;                // batch == XCD
    const int j = bid2 >> 3;               // 0..511 within batch
    const int i8l = j * 256 + threadIdx.x; // 0..131071 (x8 elems) within batch
    const size_t i8 = ((size_t)b << 17) + i8l;
    const size_t base = i8 * 8;
    const int i0 = (int)(base & 1023);
    const float4* src = (const float4*)(x + base);
    const float4 a = src[0];
    const float4 b4 = src[1];
    const float4* st = (const float4*)(style_k + b * 1024 + i0);
    const float4 t0 = st[0], t1 = st[1];
    ushort8 w;
    w[0] = f32_to_bf16(a.x * t0.x); w[1] = f32_to_bf16(a.y * t0.y);
    w[2] = f32_to_bf16(a.z * t0.z); w[3] = f32_to_bf16(a.w * t0.w);
    w[4] = f32_to_bf16(b4.x * t1.x); w[5] = f32_to_bf16(b4.y * t1.y);
    w[6] = f32_to_bf16(b4.z * t1.z); w[7] = f32_to_bf16(b4.w * t1.w);
    ((ushort8*)xmod)[i8] = w;
  }
}

// ---- batched-A, SHARED-B GEMM: C[b] = A[b] (1024xK) * Bw (1024xK)^T, epi: *dm[b,col] + bias
// BM=128, BN=128, BK=64, 4 waves (256 thr, 2x2), 64 KB LDS -> 2 blocks/CU.
// Depth-2 counted-vmcnt pipeline (8 loads/thread/tile -> vmcnt(8)), XOR swizzle.
// 1D grid 512: bz = id&7 pins each batch to one XCD (A 2MB + W 2MB = L2-resident).
// Best-measured config (R10): schedule variants (1-barrier, 3-buf, BK32, 8-wave,
// 32x32 MFMA) all regressed -- 2-phase ceiling is the structural plateau here.
template <bool OUT_BF16>
__launch_bounds__(256, 2)
__global__ void gemm_bt(const unsigned short* __restrict__ A,
                        const unsigned short* __restrict__ Bw,
                        const float* __restrict__ dm,
                        const float* __restrict__ bias,
                        void* __restrict__ C) {
  constexpr int Kd = 1024;
  constexpr int NT = Kd / 64;  // 16 K-tiles
  __shared__ unsigned short As[2 * 128 * 64];  // 32 KB
  __shared__ unsigned short Bs[2 * 128 * 64];  // 32 KB
  const int id = blockIdx.x;
  const int bz = id & 7;            // batch == XCD (round-robin dispatch)
  const int chunk = id >> 3;        // 0..63
  const int tileN = (chunk & 7) << 7;
  const int tileM = (chunk >> 3) << 7;
  const int tid = threadIdx.x;
  const int wid = tid >> 6, lane = tid & 63;
  const int wr = wid >> 1, wc = wid & 1;
  const int frow = lane & 15, hi = lane >> 4;
  const unsigned short* Ab = A + ((size_t)bz * 1024 + tileM) * Kd;
  const unsigned short* Bb = Bw + (size_t)tileN * Kd;   // shared weight

  f32x4 acc[4][4];
#pragma unroll
  for (int m = 0; m < 4; ++m)
#pragma unroll
    for (int n = 0; n < 4; ++n) acc[m][n] = (f32x4){0.f, 0.f, 0.f, 0.f};

  const int wq = wid << 6;  // wave-uniform chunk base within a 256-chunk group

  auto stage = [&](int buf, int kt) {
    // each array: 1024 chunks of 16B; 256 threads -> 4 chunks/thread/array
#pragma unroll
    for (int j = 0; j < 4; ++j) {
      const int qb = j * 256 + wq;
      const int q = qb + lane;
      const int r = q >> 3;
      const int sc = (q & 7) ^ (r & 7);
      gload_lds16(Ab + (size_t)r * Kd + kt * 64 + sc * 8, (void*)&As[buf * 8192 + qb * 8]);
    }
#pragma unroll
    for (int j = 0; j < 4; ++j) {
      const int qb = j * 256 + wq;
      const int q = qb + lane;
      const int r = q >> 3;
      const int sc = (q & 7) ^ (r & 7);
      gload_lds16(Bb + (size_t)r * Kd + kt * 64 + sc * 8, (void*)&Bs[buf * 8192 + qb * 8]);
    }
  };

  stage(0, 0);
  stage(1, 1);

  for (int kt = 0; kt < NT; ++kt) {
    const int buf = kt & 1;
    if (kt + 1 < NT) asm volatile("s_waitcnt vmcnt(8)" ::: "memory");
    else             asm volatile("s_waitcnt vmcnt(0)" ::: "memory");
    __builtin_amdgcn_s_barrier();
    asm volatile("" ::: "memory");

    bf16x8 av[4][2], bv[4][2];
#pragma unroll
    for (int m = 0; m < 4; ++m) {
      const int row = (wr << 6) + (m << 4) + frow;
#pragma unroll
      for (int ks = 0; ks < 2; ++ks) {
        const int ch = ((ks << 2) + hi) ^ (row & 7);
        av[m][ks] = *(const bf16x8*)&As[buf * 8192 + row * 64 + ch * 8];
      }
    }
#pragma unroll
    for (int n = 0; n < 4; ++n) {
      const int row = (wc << 6) + (n << 4) + frow;
#pragma unroll
      for (int ks = 0; ks < 2; ++ks) {
        const int ch = ((ks << 2) + hi) ^ (row & 7);
        bv[n][ks] = *(const bf16x8*)&Bs[buf * 8192 + row * 64 + ch * 8];
      }
    }
#pragma unroll
    for (int ks = 0; ks < 2; ++ks)
#pragma unroll
      for (int m = 0; m < 4; ++m)
#pragma unroll
        for (int n = 0; n < 4; ++n)
          acc[m][n] = __builtin_amdgcn_mfma_f32_16x16x32_bf16(av[m][ks], bv[n][ks],
                                                              acc[m][n], 0, 0, 0);
    asm volatile("s_waitcnt lgkmcnt(0)" ::: "memory");
    __builtin_amdgcn_s_barrier();
    asm volatile("" ::: "memory");
    if (kt + 2 < NT) stage(buf, kt + 2);
  }

  const int crow0 = tileM + (wr << 6);
  const int ccol0 = tileN + (wc << 6);
#pragma unroll
  for (int n = 0; n < 4; ++n) {
    const int col = ccol0 + n * 16 + frow;
    const float dm_c = dm[bz * 1024 + col];
    const float bias_c = bias[col];
#pragma unroll
    for (int m = 0; m < 4; ++m) {
#pragma unroll
      for (int i = 0; i < 4; ++i) {
        const int row = crow0 + m * 16 + (hi << 2) + i;
        const float v = acc[m][n][i] * dm_c + bias_c;
        const size_t idx = ((size_t)bz * 1024 + row) * 1024 + col;
        if constexpr (OUT_BF16)
          ((unsigned short*)C)[idx] = f32_to_bf16(v);
        else
          ((float*)C)[idx] = v;
      }
    }
  }
}

// ---- per-token 16x16 head-mix attention via MFMA (1 wave / token)
// XCD-pinned: batch = id&7 so kxb[b] reads and attb[b] writes stay in XCD b's L2.
__global__ void attn_kernel(const unsigned short* __restrict__ kx,
                            const float* __restrict__ style_o,
                            unsigned short* __restrict__ att) {
  __shared__ __align__(16) unsigned short KXt[4][64][17];  // [d][j] transposed
  __shared__ __align__(16) unsigned short Pl[4][16][24];
  __shared__ __align__(16) float Ol[4][16][68];            // [m'][d]
  const int w = threadIdx.x >> 6, lane = threadIdx.x & 63;
  const int bz = blockIdx.x & 7;                 // batch == XCD
  const int tg = blockIdx.x >> 3;                // 0..255 token-group in batch
  const int token = (bz << 10) + (tg << 2) + w;
  const int m = lane & 15, hi = lane >> 4;
  const unsigned short* src = kx + (size_t)token * 1024;

  ushort8 af0 = *(const ushort8*)(src + m * 64 + hi * 8);
  ushort8 af1 = *(const ushort8*)(src + m * 64 + 32 + hi * 8);
#pragma unroll
  for (int t = 0; t < 8; ++t) {
    KXt[w][hi * 8 + t][m] = af0[t];
    KXt[w][32 + hi * 8 + t][m] = af1[t];
  }

  f32x4 s = {0.f, 0.f, 0.f, 0.f};
  s = __builtin_amdgcn_mfma_f32_16x16x32_bf16(__builtin_bit_cast(bf16x8, af0),
                                              __builtin_bit_cast(bf16x8, af0), s, 0, 0, 0);
  s = __builtin_amdgcn_mfma_f32_16x16x32_bf16(__builtin_bit_cast(bf16x8, af1),
                                              __builtin_bit_cast(bf16x8, af1), s, 0, 0, 0);
  float v[4], mx[4], sum[4];
#pragma unroll
  for (int i = 0; i < 4; ++i) { v[i] = s[i] * 0.125f; mx[i] = v[i]; }
#pragma unroll
  for (int off = 1; off <= 8; off <<= 1)
#pragma unroll
    for (int i = 0; i < 4; ++i) mx[i] = fmaxf(mx[i], __shfl_xor(mx[i], off));
#pragma unroll
  for (int i = 0; i < 4; ++i) { v[i] = __expf(v[i] - mx[i]); sum[i] = v[i]; }
#pragma unroll
  for (int off = 1; off <= 8; off <<= 1)
#pragma unroll
    for (int i = 0; i < 4; ++i) sum[i] += __shfl_xor(sum[i], off);
#pragma unroll
  for (int i = 0; i < 4; ++i) Pl[w][4 * hi + i][m] = f32_to_bf16(v[i] / sum[i]);

  asm volatile("s_waitcnt lgkmcnt(0)" ::: "memory");
  __builtin_amdgcn_sched_barrier(0);

  const int jb = (hi & 1) << 3;
  bf16x8 pa;
  if (hi < 2) pa = *(const bf16x8*)&Pl[w][m][jb];
  else        pa = (bf16x8){0, 0, 0, 0, 0, 0, 0, 0};
#pragma unroll
  for (int blk = 0; blk < 4; ++blk) {
    const bf16x8 bb = *(const bf16x8*)&KXt[w][blk * 16 + m][jb];
    f32x4 o = {0.f, 0.f, 0.f, 0.f};
    o = __builtin_amdgcn_mfma_f32_16x16x32_bf16(pa, bb, o, 0, 0, 0);
#pragma unroll
    for (int i = 0; i < 4; ++i) Ol[w][4 * hi + i][blk * 16 + m] = o[i];
  }
  asm volatile("s_waitcnt lgkmcnt(0)" ::: "memory");
  __builtin_amdgcn_sched_barrier(0);

  const int mr = lane >> 2, d0 = (lane & 3) << 4;
  const int fbase = mr * 64 + d0;
  const float* so = style_o + (size_t)bz * 1024 + fbase;
  const float4 s0v = ((const float4*)so)[0];
  const float4 s1v = ((const float4*)so)[1];
  const float4 s2v = ((const float4*)so)[2];
  const float4 s3v = ((const float4*)so)[3];
  float ov[16];
#pragma unroll
  for (int t = 0; t < 16; ++t) ov[t] = Ol[w][mr][d0 + t];
  ov[0] *= s0v.x;  ov[1] *= s0v.y;  ov[2] *= s0v.z;  ov[3] *= s0v.w;
  ov[4] *= s1v.x;  ov[5] *= s1v.y;  ov[6] *= s1v.z;  ov[7] *= s1v.w;
  ov[8] *= s2v.x;  ov[9] *= s2v.y;  ov[10] *= s2v.z; ov[11] *= s2v.w;
  ov[12] *= s3v.x; ov[13] *= s3v.y; ov[14] *= s3v.z; ov[15] *= s3v.w;
  ushort8 w0, w1;
#pragma unroll
  for (int t = 0; t < 8; ++t) { w0[t] = f32_to_bf16(ov[t]); w1[t] = f32_to_bf16(ov[8 + t]); }
  unsigned short* dst = att + (size_t)token * 1024 + fbase;
  *(ushort8*)dst = w0;
  *(ushort8*)(dst + 8) = w1;
}

extern "C" void kernel_launch(void* const* d_in, const int* in_sizes, int n_in,
                              void* d_out, int out_size, void* d_ws, size_t ws_size,
                              hipStream_t stream) {
  const float* x     = (const float*)d_in[0];
  const float* s     = (const float*)d_in[1];
  const float* k_aff_w = (const float*)d_in[2];
  const float* k_aff_b = (const float*)d_in[3];
  const float* k_w   = (const float*)d_in[4];
  const float* k_b   = (const float*)d_in[5];
  const float* o_aff_w = (const float*)d_in[6];
  const float* o_aff_b = (const float*)d_in[7];
  const float* o_w   = (const float*)d_in[8];
  const float* o_b   = (const float*)d_in[9];
  float* out = (float*)d_out;

  char* ws = (char*)d_ws;
  float* style_k = (float*)(ws);                                  // 32 KB
  float* style_o = (float*)(ws + (32 << 10));                     // 32 KB
  float* dmk     = (float*)(ws + (64 << 10));                     // 32 KB
  float* dmo     = (float*)(ws + (96 << 10));                     // 32 KB
  unsigned short* wkb  = (unsigned short*)(ws + ((size_t)1 << 20));   // 2 MB
  unsigned short* wob  = (unsigned short*)(ws + ((size_t)3 << 20));   // 2 MB
  unsigned short* xmod = (unsigned short*)(ws + ((size_t)8 << 20));   // 16 MB
  unsigned short* kxb  = (unsigned short*)(ws + ((size_t)24 << 20));  // 16 MB
  unsigned short* attb = (unsigned short*)(ws + ((size_t)40 << 20));  // 16 MB

  style_kernel<<<512, 256, 0, stream>>>(s, k_aff_w, k_aff_b, o_aff_w, o_aff_b,
                                        style_k, style_o);
  prep_kernel<<<4608, 256, 0, stream>>>(k_w, o_w, style_k, style_o,
                                        dmk, dmo, wkb, wob, x, xmod);
  gemm_bt<true><<<512, 256, 0, stream>>>(xmod, wkb, dmk, k_b, (void*)kxb);
  attn_kernel<<<2048, 256, 0, stream>>>(kxb, style_o, attb);
  gemm_bt<false><<<512, 256, 0, stream>>>(attb, wob, dmo, o_b, (void*)out);
}